// Round 6
// baseline (615.915 us; speedup 1.0000x reference)
//
#include <hip/hip_runtime.h>
#include <hip/hip_bf16.h>

#define TT 8192
#define DD 2048
#define HH 1408
#define EE 8
#define KTOP 2
#define NA (TT * KTOP)  // 16384 assignments

typedef __attribute__((ext_vector_type(8))) short bh8;   // 8 bf16 = 4 VGPR
typedef __attribute__((ext_vector_type(4))) float f4;    // MFMA accumulator

typedef __attribute__((address_space(1))) const void gconst_t;
typedef __attribute__((address_space(3))) void lds_t;

__device__ __forceinline__ void glds16(const void* g, void* l) {
  __builtin_amdgcn_global_load_lds((gconst_t*)g, (lds_t*)l, 16, 0, 0);
}

__device__ __forceinline__ float silu_f(float x) { return x / (1.f + __expf(-x)); }

// ---------------- bookkeeping kernels ----------------
__global__ void k_init(int* counts) {
  int i = threadIdx.x;
  if (i < EE) counts[i] = 0;
}

__global__ void k_count(const int* __restrict__ idx, int* __restrict__ counts) {
  int i = blockIdx.x * 256 + threadIdx.x;
  if (i < NA) atomicAdd(&counts[idx[i]], 1);
}

__global__ void k_scan(const int* __restrict__ counts, int* __restrict__ off,
                       int* __restrict__ cursor) {
  if (threadIdx.x == 0) {
    int a = 0;
    for (int e = 0; e < EE; ++e) { off[e] = a; cursor[e] = a; a += counts[e]; }
    off[EE] = a;
  }
}

__global__ void k_scatter(const int* __restrict__ idx, const float* __restrict__ sc,
                          int* __restrict__ cursor, int* __restrict__ rows_token,
                          float* __restrict__ rows_score, int* __restrict__ pos) {
  int i = blockIdx.x * 256 + threadIdx.x;
  if (i < NA) {
    int e = idx[i];
    int p = atomicAdd(&cursor[e], 1);
    rows_token[p] = i / KTOP;
    rows_score[p] = sc[i];
    pos[i] = p;
  }
}

// ---------------- conversion kernels ----------------
__global__ void k_cvtx(const float* __restrict__ src, __hip_bfloat16* __restrict__ dst) {
  int i = blockIdx.x * 256 + threadIdx.x;  // indexes float4
  const int n4 = TT * DD / 4;
  if (i < n4) {
    float4 v = reinterpret_cast<const float4*>(src)[i];
    union { ushort4 u; __hip_bfloat16 h[4]; } o;
    o.h[0] = __float2bfloat16(v.x); o.h[1] = __float2bfloat16(v.y);
    o.h[2] = __float2bfloat16(v.z); o.h[3] = __float2bfloat16(v.w);
    reinterpret_cast<ushort4*>(dst)[i] = o.u;
  }
}

// transpose+convert v2: src fp32 [.][R][C] -> dst bf16 [.][C][R].
// Tile = 128 src-rows x 64 src-cols. Reads: 256B contiguous segments.
// Writes: each out-row written as 4x64B = 256B contiguous.
// LDS [128][65]: read-phase ~2-way, write-phase (o=tid&63) 2-way -> free.
// z selects (tensor, expert): e = z&7, sel = z>>3.
__global__ void k_tc2(const float* __restrict__ srcA, const float* __restrict__ srcB,
                      __hip_bfloat16* __restrict__ dstA, __hip_bfloat16* __restrict__ dstB,
                      int R, int C) {
  __shared__ float t[128][65];
  const int e = blockIdx.z & 7;
  const int sel = blockIdx.z >> 3;
  const float* s = (sel ? srcB : srcA) + (size_t)e * R * C;
  __hip_bfloat16* d = (sel ? dstB : dstA) + (size_t)e * R * C;
  const int c0 = blockIdx.x * 64, r0 = blockIdx.y * 128;
  const int tid = threadIdx.x;
#pragma unroll
  for (int j = 0; j < 8; ++j) {
    int f = tid + 256 * j;
    int row = f >> 4, c4 = (f & 15) << 2;
    float4 v = *reinterpret_cast<const float4*>(&s[(size_t)(r0 + row) * C + c0 + c4]);
    t[row][c4] = v.x; t[row][c4 + 1] = v.y; t[row][c4 + 2] = v.z; t[row][c4 + 3] = v.w;
  }
  __syncthreads();
  const int o = tid & 63;   // out-row within tile (src col)
  const int sg = tid >> 6;  // 0..3: which 32-elem segment
  __hip_bfloat16 ob[32];
#pragma unroll
  for (int k = 0; k < 32; ++k)
    ob[k] = __float2bfloat16(t[sg * 32 + k][o]);
  __hip_bfloat16* dp = &d[(size_t)(c0 + o) * R + r0 + sg * 32];
#pragma unroll
  for (int q = 0; q < 4; ++q)
    reinterpret_cast<uint4*>(dp)[q] = reinterpret_cast<const uint4*>(ob)[q];
}

// combine: y[t] = fp32(ybuf[pos[2t]]) + fp32(ybuf[pos[2t+1]])  (scores pre-folded)
__global__ void k_combine(const __hip_bfloat16* __restrict__ ybuf,
                          const int* __restrict__ pos, float* __restrict__ y) {
  int i = blockIdx.x * 256 + threadIdx.x;  // over TT * DD/8
  int t = i >> 8;                          // DD/8 == 256
  int d0 = (i & 255) << 3;
  const uint4 a = *reinterpret_cast<const uint4*>(ybuf + (size_t)pos[2 * t] * DD + d0);
  const uint4 b = *reinterpret_cast<const uint4*>(ybuf + (size_t)pos[2 * t + 1] * DD + d0);
  float* o = y + (size_t)t * DD + d0;
  unsigned au[4] = {a.x, a.y, a.z, a.w}, bu[4] = {b.x, b.y, b.z, b.w};
  float r[8];
#pragma unroll
  for (int j = 0; j < 4; ++j) {
    r[2 * j] = __uint_as_float(au[j] << 16) + __uint_as_float(bu[j] << 16);
    r[2 * j + 1] = __uint_as_float(au[j] & 0xffff0000u) + __uint_as_float(bu[j] & 0xffff0000u);
  }
  reinterpret_cast<float4*>(o)[0] = (float4){r[0], r[1], r[2], r[3]};
  reinterpret_cast<float4*>(o)[1] = (float4){r[4], r[5], r[6], r[7]};
}

// ---------------- GEMM1: h = silu(Xe*Wg) * (Xe*Wu) ----------------
// Round-1 proven config. Dispatched as 4 expert-pair slices (e = blockIdx.z + e0)
// so per-dispatch duration ~56us -> reveals smaller kernels in rocprof top-5.
__global__ __launch_bounds__(256, 2) void k_gemm1(
    const __hip_bfloat16* __restrict__ xb,
    const __hip_bfloat16* __restrict__ Wgb,
    const __hip_bfloat16* __restrict__ Wub,
    const int* __restrict__ rows_token,
    const int* __restrict__ off,
    __hip_bfloat16* __restrict__ hbuf,
    int e0) {
  const int e = blockIdx.z + e0;
  const int oe = off[e];
  const int ne = off[e + 1] - oe;
  if (ne <= 0) return;
  const int n0 = blockIdx.x * 64;
  const int tid = threadIdx.x;
  const int lane = tid & 63;
  const int w = tid >> 6;

  __shared__ __hip_bfloat16 As[128 * 64];
  __shared__ __hip_bfloat16 Bs[128 * 64];

  const int kel = (((lane & 7) ^ (lane >> 3)) << 3);

  const __hip_bfloat16* bsrc[4];
#pragma unroll
  for (int i = 0; i < 4; ++i) {
    int bn = ((w * 4 + i) << 3) + (lane >> 3);
    const __hip_bfloat16* base =
        (bn < 64) ? (Wgb + ((size_t)e * HH + (n0 + bn)) * DD)
                  : (Wub + ((size_t)e * HH + (n0 + bn - 64)) * DD);
    bsrc[i] = base + kel;
  }

  for (int m0 = blockIdx.y * 128; m0 < ne; m0 += gridDim.y * 128) {
    const __hip_bfloat16* asrc[4];
#pragma unroll
    for (int i = 0; i < 4; ++i) {
      int r = ((w * 4 + i) << 3) + (lane >> 3);
      int rr = m0 + r; rr = rr < ne ? rr : ne - 1;
      asrc[i] = xb + (size_t)rows_token[oe + rr] * DD + kel;
    }

    f4 acc[2][8];
#pragma unroll
    for (int mf = 0; mf < 2; ++mf)
#pragma unroll
      for (int nf = 0; nf < 8; ++nf)
        acc[mf][nf] = (f4){0.f, 0.f, 0.f, 0.f};

    for (int k0 = 0; k0 < DD; k0 += 64) {
#pragma unroll
      for (int i = 0; i < 4; ++i) {
        glds16(asrc[i] + k0, As + ((w * 4 + i) << 9));
        glds16(bsrc[i] + k0, Bs + ((w * 4 + i) << 9));
      }
      __syncthreads();
#pragma unroll
      for (int kk = 0; kk < 2; ++kk) {
        const int kByte = (kk * 32 + ((lane >> 4) << 3)) * 2;
        bh8 a[2], b[8];
#pragma unroll
        for (int mf = 0; mf < 2; ++mf) {
          int row = (w << 5) + mf * 16 + (lane & 15);
          int ad = row * 128 + (kByte ^ ((row & 7) << 4));
          a[mf] = *reinterpret_cast<const bh8*>(reinterpret_cast<const char*>(As) + ad);
        }
#pragma unroll
        for (int nf = 0; nf < 8; ++nf) {
          int bn = nf * 16 + (lane & 15);
          int ad = bn * 128 + (kByte ^ ((bn & 7) << 4));
          b[nf] = *reinterpret_cast<const bh8*>(reinterpret_cast<const char*>(Bs) + ad);
        }
#pragma unroll
        for (int mf = 0; mf < 2; ++mf)
#pragma unroll
          for (int nf = 0; nf < 8; ++nf)
            acc[mf][nf] = __builtin_amdgcn_mfma_f32_16x16x32_bf16(a[mf], b[nf], acc[mf][nf], 0, 0, 0);
      }
      __syncthreads();
    }

    const int cb = n0 + (lane & 15);
#pragma unroll
    for (int mf = 0; mf < 2; ++mf) {
#pragma unroll
      for (int reg = 0; reg < 4; ++reg) {
        int grow = m0 + (w << 5) + mf * 16 + ((lane >> 4) << 2) + reg;
        if (grow < ne) {
          size_t hb = (size_t)(oe + grow) * HH;
#pragma unroll
          for (int nf = 0; nf < 4; ++nf) {
            float g = acc[mf][nf][reg];
            float u = acc[mf][nf + 4][reg];
            hbuf[hb + cb + nf * 16] = __float2bfloat16(silu_f(g) * u);
          }
        }
      }
    }
  }
}

// ---------------- GEMM2: ybuf[row] = score * (h_e * Wd_e) in bf16 ----------------
__global__ __launch_bounds__(256, 2) void k_gemm2(
    const __hip_bfloat16* __restrict__ hbuf,
    const __hip_bfloat16* __restrict__ Wdb,
    const float* __restrict__ rows_score,
    const int* __restrict__ off,
    __hip_bfloat16* __restrict__ ybuf) {
  const int e = blockIdx.z;
  const int oe = off[e];
  const int ne = off[e + 1] - oe;
  if (ne <= 0) return;
  const int n0 = blockIdx.x * 128;
  const int tid = threadIdx.x;
  const int lane = tid & 63;
  const int w = tid >> 6;

  __shared__ __hip_bfloat16 As[128 * 64];
  __shared__ __hip_bfloat16 Bs[128 * 64];
  const int kel = (((lane & 7) ^ (lane >> 3)) << 3);

  const __hip_bfloat16* bsrc[4];
#pragma unroll
  for (int i = 0; i < 4; ++i) {
    int bn = ((w * 4 + i) << 3) + (lane >> 3);
    bsrc[i] = Wdb + ((size_t)e * DD + (n0 + bn)) * HH + kel;
  }

  for (int m0 = blockIdx.y * 128; m0 < ne; m0 += gridDim.y * 128) {
    const __hip_bfloat16* asrc[4];
#pragma unroll
    for (int i = 0; i < 4; ++i) {
      int r = ((w * 4 + i) << 3) + (lane >> 3);
      int rr = m0 + r; rr = rr < ne ? rr : ne - 1;
      asrc[i] = hbuf + (size_t)(oe + rr) * HH + kel;
    }

    f4 acc[2][8];
#pragma unroll
    for (int mf = 0; mf < 2; ++mf)
#pragma unroll
      for (int nf = 0; nf < 8; ++nf)
        acc[mf][nf] = (f4){0.f, 0.f, 0.f, 0.f};

    for (int k0 = 0; k0 < HH; k0 += 64) {
#pragma unroll
      for (int i = 0; i < 4; ++i) {
        glds16(asrc[i] + k0, As + ((w * 4 + i) << 9));
        glds16(bsrc[i] + k0, Bs + ((w * 4 + i) << 9));
      }
      __syncthreads();
#pragma unroll
      for (int kk = 0; kk < 2; ++kk) {
        const int kByte = (kk * 32 + ((lane >> 4) << 3)) * 2;
        bh8 a[2], b[8];
#pragma unroll
        for (int mf = 0; mf < 2; ++mf) {
          int row = (w << 5) + mf * 16 + (lane & 15);
          int ad = row * 128 + (kByte ^ ((row & 7) << 4));
          a[mf] = *reinterpret_cast<const bh8*>(reinterpret_cast<const char*>(As) + ad);
        }
#pragma unroll
        for (int nf = 0; nf < 8; ++nf) {
          int bn = nf * 16 + (lane & 15);
          int ad = bn * 128 + (kByte ^ ((bn & 7) << 4));
          b[nf] = *reinterpret_cast<const bh8*>(reinterpret_cast<const char*>(Bs) + ad);
        }
#pragma unroll
        for (int mf = 0; mf < 2; ++mf)
#pragma unroll
          for (int nf = 0; nf < 8; ++nf)
            acc[mf][nf] = __builtin_amdgcn_mfma_f32_16x16x32_bf16(a[mf], b[nf], acc[mf][nf], 0, 0, 0);
      }
      __syncthreads();
    }

    // epilogue: scale by gate score, write bf16 row (combined later)
#pragma unroll
    for (int mf = 0; mf < 2; ++mf) {
#pragma unroll
      for (int reg = 0; reg < 4; ++reg) {
        int grow = m0 + (w << 5) + mf * 16 + ((lane >> 4) << 2) + reg;
        if (grow < ne) {
          float sc = rows_score[oe + grow];
          __hip_bfloat16* yr = ybuf + (size_t)(oe + grow) * DD + n0 + (lane & 15);
#pragma unroll
          for (int nf = 0; nf < 8; ++nf)
            yr[nf * 16] = __float2bfloat16(sc * acc[mf][nf][reg]);
        }
      }
    }
  }
}

// ---------------- launch ----------------
extern "C" void kernel_launch(void* const* d_in, const int* in_sizes, int n_in,
                              void* d_out, int out_size, void* d_ws, size_t ws_size,
                              hipStream_t stream) {
  const float* x = (const float*)d_in[0];
  const int* topk_idx = (const int*)d_in[1];
  const float* topk_sc = (const float*)d_in[2];
  const float* Wg = (const float*)d_in[3];
  const float* Wu = (const float*)d_in[4];
  const float* Wd = (const float*)d_in[5];
  float* y = (float*)d_out;

  char* p = (char*)d_ws;
  auto take = [&](size_t b) { char* r = p; p += (b + 255) & ~(size_t)255; return r; };
  int* counts = (int*)take(EE * 4);
  int* cursor = (int*)take(EE * 4);
  int* off = (int*)take((EE + 1) * 4);
  int* rows_token = (int*)take((size_t)NA * 4);
  float* rows_score = (float*)take((size_t)NA * 4);
  int* pos = (int*)take((size_t)NA * 4);
  __hip_bfloat16* xb = (__hip_bfloat16*)take((size_t)TT * DD * 2);
  __hip_bfloat16* Wgb = (__hip_bfloat16*)take((size_t)EE * DD * HH * 2);
  __hip_bfloat16* Wub = (__hip_bfloat16*)take((size_t)EE * DD * HH * 2);
  __hip_bfloat16* Wdb = (__hip_bfloat16*)take((size_t)EE * DD * HH * 2);
  __hip_bfloat16* hbuf = (__hip_bfloat16*)take((size_t)NA * HH * 2);
  __hip_bfloat16* ybuf = (__hip_bfloat16*)take((size_t)NA * DD * 2);

  k_init<<<1, 64, 0, stream>>>(counts);
  k_count<<<NA / 256, 256, 0, stream>>>(topk_idx, counts);
  k_scan<<<1, 1, 0, stream>>>(counts, off, cursor);
  k_scatter<<<NA / 256, 256, 0, stream>>>(topk_idx, topk_sc, cursor, rows_token,
                                          rows_score, pos);
  k_cvtx<<<TT * DD / 4 / 256, 256, 0, stream>>>(x, xb);
  // Wg+Wu fused transpose (z = 2 tensors x 8 experts); Wd separate
  k_tc2<<<dim3(HH / 64, DD / 128, 16), 256, 0, stream>>>(Wg, Wu, Wgb, Wub, DD, HH);
  k_tc2<<<dim3(DD / 64, HH / 128, 8), 256, 0, stream>>>(Wd, Wd, Wdb, Wdb, HH, DD);
  for (int e0 = 0; e0 < EE; e0 += 2)
    k_gemm1<<<dim3(HH / 64, 17, 2), 256, 0, stream>>>(xb, Wgb, Wub, rows_token, off,
                                                      hbuf, e0);
  k_gemm2<<<dim3(DD / 128, 17, EE), 256, 0, stream>>>(hbuf, Wdb, rows_score, off, ybuf);
  k_combine<<<TT * (DD / 8) / 256, 256, 0, stream>>>(ybuf, pos, y);
}

// Round 7
// 473.463 us; speedup vs baseline: 1.3009x; 1.3009x over previous
//
#include <hip/hip_runtime.h>
#include <hip/hip_bf16.h>

#define TT 8192
#define DD 2048
#define HH 1408
#define EE 8
#define KTOP 2
#define NA (TT * KTOP)  // 16384 assignments

typedef __attribute__((ext_vector_type(8))) short bh8;   // 8 bf16 = 4 VGPR
typedef __attribute__((ext_vector_type(4))) float f4;    // MFMA accumulator

typedef __attribute__((address_space(1))) const void gconst_t;
typedef __attribute__((address_space(3))) void lds_t;

__device__ __forceinline__ void glds16(const void* g, void* l) {
  __builtin_amdgcn_global_load_lds((gconst_t*)g, (lds_t*)l, 16, 0, 0);
}

__device__ __forceinline__ float silu_f(float x) { return x / (1.f + __expf(-x)); }

// ---------------- fused bookkeeping: count + scan + scatter, one block ----------------
__global__ __launch_bounds__(1024) void k_book(const int* __restrict__ idx,
                                               const float* __restrict__ sc,
                                               int* __restrict__ off,
                                               int* __restrict__ rows_token,
                                               float* __restrict__ rows_score,
                                               int* __restrict__ pos) {
  __shared__ int cnt[EE];
  __shared__ int cur[EE];
  __shared__ int offs[EE + 1];
  const int tid = threadIdx.x;
  if (tid < EE) cnt[tid] = 0;
  __syncthreads();
#pragma unroll
  for (int j = 0; j < NA / 1024; ++j)
    atomicAdd(&cnt[idx[tid + j * 1024]], 1);
  __syncthreads();
  if (tid == 0) {
    int a = 0;
    for (int e = 0; e < EE; ++e) { offs[e] = a; cur[e] = a; a += cnt[e]; }
    offs[EE] = a;
  }
  __syncthreads();
  if (tid <= EE) off[tid] = offs[tid];
#pragma unroll
  for (int j = 0; j < NA / 1024; ++j) {
    int i = tid + j * 1024;
    int e = idx[i];
    int p = atomicAdd(&cur[e], 1);
    rows_token[p] = i >> 1;  // KTOP == 2
    rows_score[p] = sc[i];
    pos[i] = p;
  }
}

// ---------------- fused prep: x convert + 3 weight transpose/converts ----------------
// blocks [0,4096): x fp32->bf16, 4 float4/thread.
// blocks [4096,9728): Wg/Wu transpose tiles (128 src-rows x 64 src-cols).
// blocks [9728,12544): Wd transpose tiles.
__global__ __launch_bounds__(256) void k_prep(
    const float* __restrict__ x, __hip_bfloat16* __restrict__ xb,
    const float* __restrict__ Wg, const float* __restrict__ Wu,
    const float* __restrict__ Wd, __hip_bfloat16* __restrict__ Wgb,
    __hip_bfloat16* __restrict__ Wub, __hip_bfloat16* __restrict__ Wdb) {
  const int bid = blockIdx.x;
  const int tid = threadIdx.x;
  if (bid < 4096) {
    const float4* s4 = reinterpret_cast<const float4*>(x);
#pragma unroll
    for (int j = 0; j < 4; ++j) {
      int i = bid * 1024 + j * 256 + tid;
      float4 v = s4[i];
      union { ushort4 u; __hip_bfloat16 h[4]; } o;
      o.h[0] = __float2bfloat16(v.x); o.h[1] = __float2bfloat16(v.y);
      o.h[2] = __float2bfloat16(v.z); o.h[3] = __float2bfloat16(v.w);
      reinterpret_cast<ushort4*>(xb)[i] = o.u;
    }
    return;
  }
  __shared__ float t[128][65];
  const float* s;
  __hip_bfloat16* d;
  int R, C, rt, ct;
  if (bid < 9728) {
    int tno = bid - 4096;
    ct = tno % 22; tno /= 22;      // 22 col-tiles over HH
    rt = tno % 16; tno /= 16;      // 16 row-tiles over DD
    int e = tno & 7, sel = tno >> 3;
    R = DD; C = HH;
    s = (sel ? Wu : Wg) + (size_t)e * DD * HH;
    d = (sel ? Wub : Wgb) + (size_t)e * DD * HH;
  } else {
    int tno = bid - 9728;
    ct = tno % 32; tno /= 32;      // 32 col-tiles over DD
    rt = tno % 11; tno /= 11;      // 11 row-tiles over HH
    int e = tno;
    R = HH; C = DD;
    s = Wd + (size_t)e * DD * HH;
    d = Wdb + (size_t)e * DD * HH;
  }
  const int c0 = ct * 64, r0 = rt * 128;
#pragma unroll
  for (int j = 0; j < 8; ++j) {
    int f = tid + 256 * j;
    int row = f >> 4, c4 = (f & 15) << 2;
    float4 v = *reinterpret_cast<const float4*>(&s[(size_t)(r0 + row) * C + c0 + c4]);
    t[row][c4] = v.x; t[row][c4 + 1] = v.y; t[row][c4 + 2] = v.z; t[row][c4 + 3] = v.w;
  }
  __syncthreads();
  const int o = tid & 63;
  const int sg = tid >> 6;
  __hip_bfloat16 ob[32];
#pragma unroll
  for (int k = 0; k < 32; ++k)
    ob[k] = __float2bfloat16(t[sg * 32 + k][o]);
  __hip_bfloat16* dp = &d[(size_t)(c0 + o) * R + r0 + sg * 32];
#pragma unroll
  for (int q = 0; q < 4; ++q)
    reinterpret_cast<uint4*>(dp)[q] = reinterpret_cast<const uint4*>(ob)[q];
}

// combine: y[t] = fp32(ybuf[pos[2t]]) + fp32(ybuf[pos[2t+1]])  (scores pre-folded)
__global__ void k_combine(const __hip_bfloat16* __restrict__ ybuf,
                          const int* __restrict__ pos, float* __restrict__ y) {
  int i = blockIdx.x * 256 + threadIdx.x;  // over TT * DD/8
  int t = i >> 8;                          // DD/8 == 256
  int d0 = (i & 255) << 3;
  const uint4 a = *reinterpret_cast<const uint4*>(ybuf + (size_t)pos[2 * t] * DD + d0);
  const uint4 b = *reinterpret_cast<const uint4*>(ybuf + (size_t)pos[2 * t + 1] * DD + d0);
  float* o = y + (size_t)t * DD + d0;
  unsigned au[4] = {a.x, a.y, a.z, a.w}, bu[4] = {b.x, b.y, b.z, b.w};
  float r[8];
#pragma unroll
  for (int j = 0; j < 4; ++j) {
    r[2 * j] = __uint_as_float(au[j] << 16) + __uint_as_float(bu[j] << 16);
    r[2 * j + 1] = __uint_as_float(au[j] & 0xffff0000u) + __uint_as_float(bu[j] & 0xffff0000u);
  }
  reinterpret_cast<float4*>(o)[0] = (float4){r[0], r[1], r[2], r[3]};
  reinterpret_cast<float4*>(o)[1] = (float4){r[4], r[5], r[6], r[7]};
}

// ---------------- GEMM1: h = silu(Xe*Wg) * (Xe*Wu) ----------------
// Round-1 proven config; dispatched as 2 four-expert slices (e = blockIdx.z + e0).
__global__ __launch_bounds__(256, 2) void k_gemm1(
    const __hip_bfloat16* __restrict__ xb,
    const __hip_bfloat16* __restrict__ Wgb,
    const __hip_bfloat16* __restrict__ Wub,
    const int* __restrict__ rows_token,
    const int* __restrict__ off,
    __hip_bfloat16* __restrict__ hbuf,
    int e0) {
  const int e = blockIdx.z + e0;
  const int oe = off[e];
  const int ne = off[e + 1] - oe;
  if (ne <= 0) return;
  const int n0 = blockIdx.x * 64;
  const int tid = threadIdx.x;
  const int lane = tid & 63;
  const int w = tid >> 6;

  __shared__ __hip_bfloat16 As[128 * 64];
  __shared__ __hip_bfloat16 Bs[128 * 64];

  const int kel = (((lane & 7) ^ (lane >> 3)) << 3);

  const __hip_bfloat16* bsrc[4];
#pragma unroll
  for (int i = 0; i < 4; ++i) {
    int bn = ((w * 4 + i) << 3) + (lane >> 3);
    const __hip_bfloat16* base =
        (bn < 64) ? (Wgb + ((size_t)e * HH + (n0 + bn)) * DD)
                  : (Wub + ((size_t)e * HH + (n0 + bn - 64)) * DD);
    bsrc[i] = base + kel;
  }

  for (int m0 = blockIdx.y * 128; m0 < ne; m0 += gridDim.y * 128) {
    const __hip_bfloat16* asrc[4];
#pragma unroll
    for (int i = 0; i < 4; ++i) {
      int r = ((w * 4 + i) << 3) + (lane >> 3);
      int rr = m0 + r; rr = rr < ne ? rr : ne - 1;
      asrc[i] = xb + (size_t)rows_token[oe + rr] * DD + kel;
    }

    f4 acc[2][8];
#pragma unroll
    for (int mf = 0; mf < 2; ++mf)
#pragma unroll
      for (int nf = 0; nf < 8; ++nf)
        acc[mf][nf] = (f4){0.f, 0.f, 0.f, 0.f};

    for (int k0 = 0; k0 < DD; k0 += 64) {
#pragma unroll
      for (int i = 0; i < 4; ++i) {
        glds16(asrc[i] + k0, As + ((w * 4 + i) << 9));
        glds16(bsrc[i] + k0, Bs + ((w * 4 + i) << 9));
      }
      __syncthreads();
#pragma unroll
      for (int kk = 0; kk < 2; ++kk) {
        const int kByte = (kk * 32 + ((lane >> 4) << 3)) * 2;
        bh8 a[2], b[8];
#pragma unroll
        for (int mf = 0; mf < 2; ++mf) {
          int row = (w << 5) + mf * 16 + (lane & 15);
          int ad = row * 128 + (kByte ^ ((row & 7) << 4));
          a[mf] = *reinterpret_cast<const bh8*>(reinterpret_cast<const char*>(As) + ad);
        }
#pragma unroll
        for (int nf = 0; nf < 8; ++nf) {
          int bn = nf * 16 + (lane & 15);
          int ad = bn * 128 + (kByte ^ ((bn & 7) << 4));
          b[nf] = *reinterpret_cast<const bh8*>(reinterpret_cast<const char*>(Bs) + ad);
        }
#pragma unroll
        for (int mf = 0; mf < 2; ++mf)
#pragma unroll
          for (int nf = 0; nf < 8; ++nf)
            acc[mf][nf] = __builtin_amdgcn_mfma_f32_16x16x32_bf16(a[mf], b[nf], acc[mf][nf], 0, 0, 0);
      }
      __syncthreads();
    }

    const int cb = n0 + (lane & 15);
#pragma unroll
    for (int mf = 0; mf < 2; ++mf) {
#pragma unroll
      for (int reg = 0; reg < 4; ++reg) {
        int grow = m0 + (w << 5) + mf * 16 + ((lane >> 4) << 2) + reg;
        if (grow < ne) {
          size_t hb = (size_t)(oe + grow) * HH;
#pragma unroll
          for (int nf = 0; nf < 4; ++nf) {
            float g = acc[mf][nf][reg];
            float u = acc[mf][nf + 4][reg];
            hbuf[hb + cb + nf * 16] = __float2bfloat16(silu_f(g) * u);
          }
        }
      }
    }
  }
}

// ---------------- GEMM2: ybuf[row] = score * (h_e * Wd_e) in bf16 ----------------
__global__ __launch_bounds__(256, 2) void k_gemm2(
    const __hip_bfloat16* __restrict__ hbuf,
    const __hip_bfloat16* __restrict__ Wdb,
    const float* __restrict__ rows_score,
    const int* __restrict__ off,
    __hip_bfloat16* __restrict__ ybuf) {
  const int e = blockIdx.z;
  const int oe = off[e];
  const int ne = off[e + 1] - oe;
  if (ne <= 0) return;
  const int n0 = blockIdx.x * 128;
  const int tid = threadIdx.x;
  const int lane = tid & 63;
  const int w = tid >> 6;

  __shared__ __hip_bfloat16 As[128 * 64];
  __shared__ __hip_bfloat16 Bs[128 * 64];
  const int kel = (((lane & 7) ^ (lane >> 3)) << 3);

  const __hip_bfloat16* bsrc[4];
#pragma unroll
  for (int i = 0; i < 4; ++i) {
    int bn = ((w * 4 + i) << 3) + (lane >> 3);
    bsrc[i] = Wdb + ((size_t)e * DD + (n0 + bn)) * HH + kel;
  }

  for (int m0 = blockIdx.y * 128; m0 < ne; m0 += gridDim.y * 128) {
    const __hip_bfloat16* asrc[4];
#pragma unroll
    for (int i = 0; i < 4; ++i) {
      int r = ((w * 4 + i) << 3) + (lane >> 3);
      int rr = m0 + r; rr = rr < ne ? rr : ne - 1;
      asrc[i] = hbuf + (size_t)(oe + rr) * HH + kel;
    }

    f4 acc[2][8];
#pragma unroll
    for (int mf = 0; mf < 2; ++mf)
#pragma unroll
      for (int nf = 0; nf < 8; ++nf)
        acc[mf][nf] = (f4){0.f, 0.f, 0.f, 0.f};

    for (int k0 = 0; k0 < HH; k0 += 64) {
#pragma unroll
      for (int i = 0; i < 4; ++i) {
        glds16(asrc[i] + k0, As + ((w * 4 + i) << 9));
        glds16(bsrc[i] + k0, Bs + ((w * 4 + i) << 9));
      }
      __syncthreads();
#pragma unroll
      for (int kk = 0; kk < 2; ++kk) {
        const int kByte = (kk * 32 + ((lane >> 4) << 3)) * 2;
        bh8 a[2], b[8];
#pragma unroll
        for (int mf = 0; mf < 2; ++mf) {
          int row = (w << 5) + mf * 16 + (lane & 15);
          int ad = row * 128 + (kByte ^ ((row & 7) << 4));
          a[mf] = *reinterpret_cast<const bh8*>(reinterpret_cast<const char*>(As) + ad);
        }
#pragma unroll
        for (int nf = 0; nf < 8; ++nf) {
          int bn = nf * 16 + (lane & 15);
          int ad = bn * 128 + (kByte ^ ((bn & 7) << 4));
          b[nf] = *reinterpret_cast<const bh8*>(reinterpret_cast<const char*>(Bs) + ad);
        }
#pragma unroll
        for (int mf = 0; mf < 2; ++mf)
#pragma unroll
          for (int nf = 0; nf < 8; ++nf)
            acc[mf][nf] = __builtin_amdgcn_mfma_f32_16x16x32_bf16(a[mf], b[nf], acc[mf][nf], 0, 0, 0);
      }
      __syncthreads();
    }

    // epilogue: scale by gate score, write bf16 row (combined later)
#pragma unroll
    for (int mf = 0; mf < 2; ++mf) {
#pragma unroll
      for (int reg = 0; reg < 4; ++reg) {
        int grow = m0 + (w << 5) + mf * 16 + ((lane >> 4) << 2) + reg;
        if (grow < ne) {
          float sc = rows_score[oe + grow];
          __hip_bfloat16* yr = ybuf + (size_t)(oe + grow) * DD + n0 + (lane & 15);
#pragma unroll
          for (int nf = 0; nf < 8; ++nf)
            yr[nf * 16] = __float2bfloat16(sc * acc[mf][nf][reg]);
        }
      }
    }
  }
}

// ---------------- launch ----------------
extern "C" void kernel_launch(void* const* d_in, const int* in_sizes, int n_in,
                              void* d_out, int out_size, void* d_ws, size_t ws_size,
                              hipStream_t stream) {
  const float* x = (const float*)d_in[0];
  const int* topk_idx = (const int*)d_in[1];
  const float* topk_sc = (const float*)d_in[2];
  const float* Wg = (const float*)d_in[3];
  const float* Wu = (const float*)d_in[4];
  const float* Wd = (const float*)d_in[5];
  float* y = (float*)d_out;

  char* p = (char*)d_ws;
  auto take = [&](size_t b) { char* r = p; p += (b + 255) & ~(size_t)255; return r; };
  int* off = (int*)take((EE + 1) * 4);
  int* rows_token = (int*)take((size_t)NA * 4);
  float* rows_score = (float*)take((size_t)NA * 4);
  int* pos = (int*)take((size_t)NA * 4);
  __hip_bfloat16* xb = (__hip_bfloat16*)take((size_t)TT * DD * 2);
  __hip_bfloat16* Wgb = (__hip_bfloat16*)take((size_t)EE * DD * HH * 2);
  __hip_bfloat16* Wub = (__hip_bfloat16*)take((size_t)EE * DD * HH * 2);
  __hip_bfloat16* Wdb = (__hip_bfloat16*)take((size_t)EE * DD * HH * 2);
  __hip_bfloat16* hbuf = (__hip_bfloat16*)take((size_t)NA * HH * 2);
  __hip_bfloat16* ybuf = (__hip_bfloat16*)take((size_t)NA * DD * 2);

  k_book<<<1, 1024, 0, stream>>>(topk_idx, topk_sc, off, rows_token, rows_score, pos);
  k_prep<<<12544, 256, 0, stream>>>(x, xb, Wg, Wu, Wd, Wgb, Wub, Wdb);
  k_gemm1<<<dim3(HH / 64, 17, 4), 256, 0, stream>>>(xb, Wgb, Wub, rows_token, off,
                                                    hbuf, 0);
  k_gemm1<<<dim3(HH / 64, 17, 4), 256, 0, stream>>>(xb, Wgb, Wub, rows_token, off,
                                                    hbuf, 4);
  k_gemm2<<<dim3(DD / 128, 17, EE), 256, 0, stream>>>(hbuf, Wdb, rows_score, off, ybuf);
  k_combine<<<TT * (DD / 8) / 256, 256, 0, stream>>>(ybuf, pos, y);
}

// Round 8
// 468.073 us; speedup vs baseline: 1.3159x; 1.0115x over previous
//
#include <hip/hip_runtime.h>
#include <hip/hip_bf16.h>

#define TT 8192
#define DD 2048
#define HH 1408
#define EE 8
#define KTOP 2
#define NA (TT * KTOP)  // 16384 assignments

typedef __attribute__((ext_vector_type(8))) short bh8;   // 8 bf16 = 4 VGPR
typedef __attribute__((ext_vector_type(4))) float f4;    // MFMA accumulator

typedef __attribute__((address_space(1))) const void gconst_t;
typedef __attribute__((address_space(3))) void lds_t;

__device__ __forceinline__ void glds16(const void* g, void* l) {
  __builtin_amdgcn_global_load_lds((gconst_t*)g, (lds_t*)l, 16, 0, 0);
}

__device__ __forceinline__ float silu_f(float x) { return x / (1.f + __expf(-x)); }

__device__ __forceinline__ unsigned short bf16_bits(float x) {
  __hip_bfloat16 h = __float2bfloat16(x);
  return *reinterpret_cast<unsigned short*>(&h);
}

// ---------------- fused bookkeeping: count + scan + scatter, one block ----------------
__global__ __launch_bounds__(1024) void k_book(const int* __restrict__ idx,
                                               const float* __restrict__ sc,
                                               int* __restrict__ off,
                                               int* __restrict__ rows_token,
                                               float* __restrict__ rows_score,
                                               int* __restrict__ pos) {
  __shared__ int cnt[EE];
  __shared__ int cur[EE];
  __shared__ int offs[EE + 1];
  const int tid = threadIdx.x;
  if (tid < EE) cnt[tid] = 0;
  __syncthreads();
#pragma unroll
  for (int j = 0; j < NA / 1024; ++j)
    atomicAdd(&cnt[idx[tid + j * 1024]], 1);
  __syncthreads();
  if (tid == 0) {
    int a = 0;
    for (int e = 0; e < EE; ++e) { offs[e] = a; cur[e] = a; a += cnt[e]; }
    offs[EE] = a;
  }
  __syncthreads();
  if (tid <= EE) off[tid] = offs[tid];
#pragma unroll
  for (int j = 0; j < NA / 1024; ++j) {
    int i = tid + j * 1024;
    int e = idx[i];
    int p = atomicAdd(&cur[e], 1);
    rows_token[p] = i >> 1;  // KTOP == 2
    rows_score[p] = sc[i];
    pos[i] = p;
  }
}

// ---------------- fused prep v2: x convert + 3 weight transpose/converts ----------------
// 512 threads. blocks [0,2048): x fp32->bf16 streaming.
// blocks [2048,4864): Wg/Wu transpose, 128x128 tiles (2816 = 11ct*16rt*16(e,sel)).
// blocks [4864,6272): Wd transpose (1408 = 16ct*11rt*8e).
// Write phase: each wave-instruction stores a CONTIGUOUS 256B out-row segment
// (lane = 2 packed bf16) -- removes the 16B/4KB-stride scatter that held the
// round-7 version to 2.5 TB/s.
__global__ __launch_bounds__(512) void k_prep(
    const float* __restrict__ x, __hip_bfloat16* __restrict__ xb,
    const float* __restrict__ Wg, const float* __restrict__ Wu,
    const float* __restrict__ Wd, __hip_bfloat16* __restrict__ Wgb,
    __hip_bfloat16* __restrict__ Wub, __hip_bfloat16* __restrict__ Wdb) {
  const int bid = blockIdx.x;
  const int tid = threadIdx.x;
  if (bid < 2048) {
    const float4* s4 = reinterpret_cast<const float4*>(x);
#pragma unroll
    for (int j = 0; j < 4; ++j) {
      int i = bid * 2048 + j * 512 + tid;
      float4 v = s4[i];
      union { ushort4 u; __hip_bfloat16 h[4]; } o;
      o.h[0] = __float2bfloat16(v.x); o.h[1] = __float2bfloat16(v.y);
      o.h[2] = __float2bfloat16(v.z); o.h[3] = __float2bfloat16(v.w);
      reinterpret_cast<ushort4*>(xb)[i] = o.u;
    }
    return;
  }
  __shared__ float t[128][129];
  const float* s;
  __hip_bfloat16* d;
  int R, C, rt, ct;
  if (bid < 4864) {
    int tno = bid - 2048;
    ct = tno % 11; tno /= 11;      // 11 col-tiles of 128 over HH
    rt = tno % 16; tno /= 16;      // 16 row-tiles of 128 over DD
    int e = tno & 7, sel = tno >> 3;
    R = DD; C = HH;
    s = (sel ? Wu : Wg) + (size_t)e * DD * HH;
    d = (sel ? Wub : Wgb) + (size_t)e * DD * HH;
  } else {
    int tno = bid - 4864;
    ct = tno % 16; tno /= 16;      // 16 col-tiles over DD
    rt = tno % 11; tno /= 11;      // 11 row-tiles over HH
    int e = tno;
    R = HH; C = DD;
    s = Wd + (size_t)e * DD * HH;
    d = Wdb + (size_t)e * DD * HH;
  }
  const int c0 = ct * 128, r0 = rt * 128;
  // read: 128 rows x 512B, fully coalesced (32 lanes x float4 per row)
#pragma unroll
  for (int j = 0; j < 8; ++j) {
    int f = tid + 512 * j;
    int row = f >> 5, c4 = (f & 31) << 2;
    float4 v = *reinterpret_cast<const float4*>(&s[(size_t)(r0 + row) * C + c0 + c4]);
    t[row][c4] = v.x; t[row][c4 + 1] = v.y; t[row][c4 + 2] = v.z; t[row][c4 + 3] = v.w;
  }
  __syncthreads();
  // write: out row j (src col), wave writes 256B contiguous (lane = 2 bf16)
  const int l = tid & 63;
  const int wv = tid >> 6;
#pragma unroll
  for (int pp = 0; pp < 16; ++pp) {
    int j = wv + (pp << 3);
    unsigned lo = bf16_bits(t[2 * l][j]);
    unsigned hi = bf16_bits(t[2 * l + 1][j]);
    unsigned* dp = reinterpret_cast<unsigned*>(d + (size_t)(c0 + j) * R + r0);
    dp[l] = lo | (hi << 16);
  }
}

// combine: y[t] = fp32(ybuf[pos[2t]]) + fp32(ybuf[pos[2t+1]])  (scores pre-folded)
__global__ void k_combine(const __hip_bfloat16* __restrict__ ybuf,
                          const int* __restrict__ pos, float* __restrict__ y) {
  int i = blockIdx.x * 256 + threadIdx.x;  // over TT * DD/8
  int t = i >> 8;                          // DD/8 == 256
  int d0 = (i & 255) << 3;
  const uint4 a = *reinterpret_cast<const uint4*>(ybuf + (size_t)pos[2 * t] * DD + d0);
  const uint4 b = *reinterpret_cast<const uint4*>(ybuf + (size_t)pos[2 * t + 1] * DD + d0);
  float* o = y + (size_t)t * DD + d0;
  unsigned au[4] = {a.x, a.y, a.z, a.w}, bu[4] = {b.x, b.y, b.z, b.w};
  float r[8];
#pragma unroll
  for (int j = 0; j < 4; ++j) {
    r[2 * j] = __uint_as_float(au[j] << 16) + __uint_as_float(bu[j] << 16);
    r[2 * j + 1] = __uint_as_float(au[j] & 0xffff0000u) + __uint_as_float(bu[j] & 0xffff0000u);
  }
  reinterpret_cast<float4*>(o)[0] = (float4){r[0], r[1], r[2], r[3]};
  reinterpret_cast<float4*>(o)[1] = (float4){r[4], r[5], r[6], r[7]};
}

// ---------------- GEMM1: h = silu(Xe*Wg) * (Xe*Wu) ----------------
// Round-1 proven config; dispatched as 2 four-expert slices (e = blockIdx.z + e0).
__global__ __launch_bounds__(256, 2) void k_gemm1(
    const __hip_bfloat16* __restrict__ xb,
    const __hip_bfloat16* __restrict__ Wgb,
    const __hip_bfloat16* __restrict__ Wub,
    const int* __restrict__ rows_token,
    const int* __restrict__ off,
    __hip_bfloat16* __restrict__ hbuf,
    int e0) {
  const int e = blockIdx.z + e0;
  const int oe = off[e];
  const int ne = off[e + 1] - oe;
  if (ne <= 0) return;
  const int n0 = blockIdx.x * 64;
  const int tid = threadIdx.x;
  const int lane = tid & 63;
  const int w = tid >> 6;

  __shared__ __hip_bfloat16 As[128 * 64];
  __shared__ __hip_bfloat16 Bs[128 * 64];

  const int kel = (((lane & 7) ^ (lane >> 3)) << 3);

  const __hip_bfloat16* bsrc[4];
#pragma unroll
  for (int i = 0; i < 4; ++i) {
    int bn = ((w * 4 + i) << 3) + (lane >> 3);
    const __hip_bfloat16* base =
        (bn < 64) ? (Wgb + ((size_t)e * HH + (n0 + bn)) * DD)
                  : (Wub + ((size_t)e * HH + (n0 + bn - 64)) * DD);
    bsrc[i] = base + kel;
  }

  for (int m0 = blockIdx.y * 128; m0 < ne; m0 += gridDim.y * 128) {
    const __hip_bfloat16* asrc[4];
#pragma unroll
    for (int i = 0; i < 4; ++i) {
      int r = ((w * 4 + i) << 3) + (lane >> 3);
      int rr = m0 + r; rr = rr < ne ? rr : ne - 1;
      asrc[i] = xb + (size_t)rows_token[oe + rr] * DD + kel;
    }

    f4 acc[2][8];
#pragma unroll
    for (int mf = 0; mf < 2; ++mf)
#pragma unroll
      for (int nf = 0; nf < 8; ++nf)
        acc[mf][nf] = (f4){0.f, 0.f, 0.f, 0.f};

    for (int k0 = 0; k0 < DD; k0 += 64) {
#pragma unroll
      for (int i = 0; i < 4; ++i) {
        glds16(asrc[i] + k0, As + ((w * 4 + i) << 9));
        glds16(bsrc[i] + k0, Bs + ((w * 4 + i) << 9));
      }
      __syncthreads();
#pragma unroll
      for (int kk = 0; kk < 2; ++kk) {
        const int kByte = (kk * 32 + ((lane >> 4) << 3)) * 2;
        bh8 a[2], b[8];
#pragma unroll
        for (int mf = 0; mf < 2; ++mf) {
          int row = (w << 5) + mf * 16 + (lane & 15);
          int ad = row * 128 + (kByte ^ ((row & 7) << 4));
          a[mf] = *reinterpret_cast<const bh8*>(reinterpret_cast<const char*>(As) + ad);
        }
#pragma unroll
        for (int nf = 0; nf < 8; ++nf) {
          int bn = nf * 16 + (lane & 15);
          int ad = bn * 128 + (kByte ^ ((bn & 7) << 4));
          b[nf] = *reinterpret_cast<const bh8*>(reinterpret_cast<const char*>(Bs) + ad);
        }
#pragma unroll
        for (int mf = 0; mf < 2; ++mf)
#pragma unroll
          for (int nf = 0; nf < 8; ++nf)
            acc[mf][nf] = __builtin_amdgcn_mfma_f32_16x16x32_bf16(a[mf], b[nf], acc[mf][nf], 0, 0, 0);
      }
      __syncthreads();
    }

    const int cb = n0 + (lane & 15);
#pragma unroll
    for (int mf = 0; mf < 2; ++mf) {
#pragma unroll
      for (int reg = 0; reg < 4; ++reg) {
        int grow = m0 + (w << 5) + mf * 16 + ((lane >> 4) << 2) + reg;
        if (grow < ne) {
          size_t hb = (size_t)(oe + grow) * HH;
#pragma unroll
          for (int nf = 0; nf < 4; ++nf) {
            float g = acc[mf][nf][reg];
            float u = acc[mf][nf + 4][reg];
            hbuf[hb + cb + nf * 16] = __float2bfloat16(silu_f(g) * u);
          }
        }
      }
    }
  }
}

// ---------------- GEMM2: ybuf[row] = score * (h_e * Wd_e) in bf16 ----------------
__global__ __launch_bounds__(256, 2) void k_gemm2(
    const __hip_bfloat16* __restrict__ hbuf,
    const __hip_bfloat16* __restrict__ Wdb,
    const float* __restrict__ rows_score,
    const int* __restrict__ off,
    __hip_bfloat16* __restrict__ ybuf) {
  const int e = blockIdx.z;
  const int oe = off[e];
  const int ne = off[e + 1] - oe;
  if (ne <= 0) return;
  const int n0 = blockIdx.x * 128;
  const int tid = threadIdx.x;
  const int lane = tid & 63;
  const int w = tid >> 6;

  __shared__ __hip_bfloat16 As[128 * 64];
  __shared__ __hip_bfloat16 Bs[128 * 64];
  const int kel = (((lane & 7) ^ (lane >> 3)) << 3);

  const __hip_bfloat16* bsrc[4];
#pragma unroll
  for (int i = 0; i < 4; ++i) {
    int bn = ((w * 4 + i) << 3) + (lane >> 3);
    bsrc[i] = Wdb + ((size_t)e * DD + (n0 + bn)) * HH + kel;
  }

  for (int m0 = blockIdx.y * 128; m0 < ne; m0 += gridDim.y * 128) {
    const __hip_bfloat16* asrc[4];
#pragma unroll
    for (int i = 0; i < 4; ++i) {
      int r = ((w * 4 + i) << 3) + (lane >> 3);
      int rr = m0 + r; rr = rr < ne ? rr : ne - 1;
      asrc[i] = hbuf + (size_t)(oe + rr) * HH + kel;
    }

    f4 acc[2][8];
#pragma unroll
    for (int mf = 0; mf < 2; ++mf)
#pragma unroll
      for (int nf = 0; nf < 8; ++nf)
        acc[mf][nf] = (f4){0.f, 0.f, 0.f, 0.f};

    for (int k0 = 0; k0 < HH; k0 += 64) {
#pragma unroll
      for (int i = 0; i < 4; ++i) {
        glds16(asrc[i] + k0, As + ((w * 4 + i) << 9));
        glds16(bsrc[i] + k0, Bs + ((w * 4 + i) << 9));
      }
      __syncthreads();
#pragma unroll
      for (int kk = 0; kk < 2; ++kk) {
        const int kByte = (kk * 32 + ((lane >> 4) << 3)) * 2;
        bh8 a[2], b[8];
#pragma unroll
        for (int mf = 0; mf < 2; ++mf) {
          int row = (w << 5) + mf * 16 + (lane & 15);
          int ad = row * 128 + (kByte ^ ((row & 7) << 4));
          a[mf] = *reinterpret_cast<const bh8*>(reinterpret_cast<const char*>(As) + ad);
        }
#pragma unroll
        for (int nf = 0; nf < 8; ++nf) {
          int bn = nf * 16 + (lane & 15);
          int ad = bn * 128 + (kByte ^ ((bn & 7) << 4));
          b[nf] = *reinterpret_cast<const bh8*>(reinterpret_cast<const char*>(Bs) + ad);
        }
#pragma unroll
        for (int mf = 0; mf < 2; ++mf)
#pragma unroll
          for (int nf = 0; nf < 8; ++nf)
            acc[mf][nf] = __builtin_amdgcn_mfma_f32_16x16x32_bf16(a[mf], b[nf], acc[mf][nf], 0, 0, 0);
      }
      __syncthreads();
    }

    // epilogue: scale by gate score, write bf16 row (combined later)
#pragma unroll
    for (int mf = 0; mf < 2; ++mf) {
#pragma unroll
      for (int reg = 0; reg < 4; ++reg) {
        int grow = m0 + (w << 5) + mf * 16 + ((lane >> 4) << 2) + reg;
        if (grow < ne) {
          float sc = rows_score[oe + grow];
          __hip_bfloat16* yr = ybuf + (size_t)(oe + grow) * DD + n0 + (lane & 15);
#pragma unroll
          for (int nf = 0; nf < 8; ++nf)
            yr[nf * 16] = __float2bfloat16(sc * acc[mf][nf][reg]);
        }
      }
    }
  }
}

// ---------------- launch ----------------
extern "C" void kernel_launch(void* const* d_in, const int* in_sizes, int n_in,
                              void* d_out, int out_size, void* d_ws, size_t ws_size,
                              hipStream_t stream) {
  const float* x = (const float*)d_in[0];
  const int* topk_idx = (const int*)d_in[1];
  const float* topk_sc = (const float*)d_in[2];
  const float* Wg = (const float*)d_in[3];
  const float* Wu = (const float*)d_in[4];
  const float* Wd = (const float*)d_in[5];
  float* y = (float*)d_out;

  char* p = (char*)d_ws;
  auto take = [&](size_t b) { char* r = p; p += (b + 255) & ~(size_t)255; return r; };
  int* off = (int*)take((EE + 1) * 4);
  int* rows_token = (int*)take((size_t)NA * 4);
  float* rows_score = (float*)take((size_t)NA * 4);
  int* pos = (int*)take((size_t)NA * 4);
  __hip_bfloat16* xb = (__hip_bfloat16*)take((size_t)TT * DD * 2);
  __hip_bfloat16* Wgb = (__hip_bfloat16*)take((size_t)EE * DD * HH * 2);
  __hip_bfloat16* Wub = (__hip_bfloat16*)take((size_t)EE * DD * HH * 2);
  __hip_bfloat16* Wdb = (__hip_bfloat16*)take((size_t)EE * DD * HH * 2);
  __hip_bfloat16* hbuf = (__hip_bfloat16*)take((size_t)NA * HH * 2);
  __hip_bfloat16* ybuf = (__hip_bfloat16*)take((size_t)NA * DD * 2);

  k_book<<<1, 1024, 0, stream>>>(topk_idx, topk_sc, off, rows_token, rows_score, pos);
  k_prep<<<6272, 512, 0, stream>>>(x, xb, Wg, Wu, Wd, Wgb, Wub, Wdb);
  k_gemm1<<<dim3(HH / 64, 17, 4), 256, 0, stream>>>(xb, Wgb, Wub, rows_token, off,
                                                    hbuf, 0);
  k_gemm1<<<dim3(HH / 64, 17, 4), 256, 0, stream>>>(xb, Wgb, Wub, rows_token, off,
                                                    hbuf, 4);
  k_gemm2<<<dim3(DD / 128, 17, EE), 256, 0, stream>>>(hbuf, Wdb, rows_score, off, ybuf);
  k_combine<<<TT * (DD / 8) / 256, 256, 0, stream>>>(ybuf, pos, y);
}